// Round 7
// baseline (431.695 us; speedup 1.0000x reference)
//
#include <hip/hip_runtime.h>

#define NCOLS 16
#define NPAIR 120                      // C(16,2)
#define NTRIP 560                      // C(16,3)
#define OUTC  (NCOLS + NPAIR + NTRIP)  // 696 = 174 float4
#define NQUAD 174                      // float4s per row
#define QITER 11                       // ceil(174/16) iterations of 16 sublanes

typedef float  vfloat4 __attribute__((ext_vector_type(4)));
typedef unsigned int vuint4 __attribute__((ext_vector_type(4)));

// Column table: one u32 per column = i | j<<8 | k<<16 | op<<24
//   op 0: x[i];  op 1: T(x[i],x[j]);  op 2: T(T(x[i],x[j]),x[k])
// Stored as vuint4 per float4-quad for aligned 16B loads (L1-resident, 2.8 KB).
struct ColTab { vuint4 q[QITER * 16]; };  // 176 quads (174 real + 2 pad)

constexpr ColTab make_cols() {
    ColTab t{};
    unsigned tmp[QITER * 16 * 4] = {};
    int qn = 0;
    for (int i = 0; i < NCOLS; ++i)
        tmp[qn++] = (unsigned)i;                                   // op 0
    for (int i = 0; i < NCOLS; ++i)
        for (int j = i + 1; j < NCOLS; ++j)
            tmp[qn++] = (unsigned)i | ((unsigned)j << 8) | (1u << 24);
    for (int i = 0; i < NCOLS; ++i)
        for (int j = i + 1; j < NCOLS; ++j)
            for (int k = j + 1; k < NCOLS; ++k)
                tmp[qn++] = (unsigned)i | ((unsigned)j << 8) | ((unsigned)k << 16) | (2u << 24);
    for (int f = 0; f < QITER * 16; ++f) {
        t.q[f][0] = tmp[4 * f + 0];
        t.q[f][1] = tmp[4 * f + 1];
        t.q[f][2] = tmp[4 * f + 2];
        t.q[f][3] = tmp[4 * f + 3];
    }
    return t;
}

__device__ const ColTab d_cols = make_cols();

__device__ __forceinline__ float tnorm(float a, float b, float lam) {
    float m = fmaxf(fmaxf(a, b), lam);          // -> v_max3_f32
    return a * b * __builtin_amdgcn_rcpf(m);
}

__device__ __forceinline__ float colval(unsigned e, float v, int gbase, float lam) {
    float a = __shfl(v, gbase + (int)(e & 15u));
    float b = __shfl(v, gbase + (int)((e >> 8) & 15u));
    float c = __shfl(v, gbase + (int)((e >> 16) & 15u));
    float t1 = tnorm(a, b, lam);
    float t2 = tnorm(t1, c, lam);
    unsigned op = e >> 24;
    return (op == 0u) ? a : ((op == 1u) ? t1 : t2);
}

__global__ __launch_bounds__(256) void dubois_kernel(
    const float* __restrict__ x, const float* __restrict__ lam_p,
    float* __restrict__ out, int ngroups, int iters, int nwaves)
{
    const int lane  = threadIdx.x & 63;
    const int sub   = lane & 15;     // sublane within 16-lane row group
    const int gbase = lane & 48;     // first lane of my group
    const int gwave = (blockIdx.x * blockDim.x + threadIdx.x) >> 6;
    const float lam = lam_p[0];

    for (int it = 0; it < iters; ++it) {
        const int grp = gwave + it * nwaves;     // 4-row group id
        if (grp >= ngroups) break;

        // 64 lanes read 64 consecutive floats = rows 4g..4g+3 (256B coalesced);
        // lanes of group g hold row 4*grp+g in lanes gbase..gbase+15
        float v = x[(size_t)grp * 64 + lane];

        const int myrow = grp * 4 + (lane >> 4);
        vfloat4* __restrict__ orow4 = reinterpret_cast<vfloat4*>(out + (size_t)myrow * OUTC);

        #pragma unroll
        for (int r = 0; r < QITER; ++r) {
            const int f = r * 16 + sub;          // float4 index within my row (<176)
            const vuint4 e = d_cols.q[f];
            vfloat4 o;
            o[0] = colval(e[0], v, gbase, lam);
            o[1] = colval(e[1], v, gbase, lam);
            o[2] = colval(e[2], v, gbase, lam);
            o[3] = colval(e[3], v, gbase, lam);
            if (r < QITER - 1 || f < NQUAD)      // folds at compile time for r<10
                __builtin_nontemporal_store(o, orow4 + f);
        }
    }
}

extern "C" void kernel_launch(void* const* d_in, const int* in_sizes, int n_in,
                              void* d_out, int out_size, void* d_ws, size_t ws_size,
                              hipStream_t stream) {
    const float* x   = (const float*)d_in[0];
    const float* lam = (const float*)d_in[1];
    float* out = (float*)d_out;

    const int B = in_sizes[0] / NCOLS;           // 131072 rows
    const int ngroups = B / 4;                   // 32768 4-row groups (B % 4 == 0)
    const int threads = 256;
    const int blocks  = 2048;                    // 8 blocks/CU
    const int nwaves  = blocks * (threads / 64); // 8192 waves
    const int iters   = (ngroups + nwaves - 1) / nwaves;  // 4

    dubois_kernel<<<blocks, threads, 0, stream>>>(x, lam, out, ngroups, iters, nwaves);
}